// Round 5
// baseline (125.279 us; speedup 1.0000x reference)
//
#include <hip/hip_runtime.h>

// input_tensor: [8,128,128,128,1] fp32 ; random_u: [8,8,3] fp32 ; SCALE=0.2
#define NB   8
#define NS   128
#define VOX  (NS*NS*NS)

// R5: tile 32w x 8h x 4d. Affine coeff bounds (A^T A = 8I closed form):
//   t_diag in [0.8,1.0], |t_offdiag| <= 0.1, |t_trans| <= 0.1.
// Spans over tile offsets (kd<=3, kh<=7, kw<=31):
//   p0 span <= 3*1 + 7*0.1 + 31*0.1 = 6.8  -> floor span <= 7 -> SD = 9 rows
//   p1 span <= 3*0.1 + 7*1 + 31*0.1 = 10.4 -> floor span <= 11 -> SH = 13 rows
//   p2 span <= 3*0.1 + 7*0.1 + 31*1 = 32.0 -> cols <= 34 (+align) -> ROW_W = 40
// SLAB = 9*13*40*4 = 18,720 B -> 8 blocks/CU = 32 waves/CU (the HW cap).
// Rationale: R2 proved resident-wave TLP is the binding resource (54KB dbuf
// halved occupancy -> +17% time despite -60% fetch). R5 buys occupancy with a
// smaller d-extent; the halved per-thread work is compensated by hoisting the
// transform into a tiny pre-kernel. R4's d_ws dependency is removed (suspected
// container-kill if workspace is null): coefficients live in a __device__
// global, written by the pre-kernel on the same stream.
// ZERO-BOUNDARY UNIFICATION (R1, verified): unclamped window; boundary blocks
// zero-fill the slab and stage only fully-valid 16B chunks -> one compute path.
#define SD    9
#define SH    13
#define ROW_W 40
#define RST   (SH*ROW_W)     // 520
#define SLAB  (SD*RST)       // 4680 floats = 18,720 B

typedef __attribute__((address_space(1))) const void gconst_t;
typedef __attribute__((address_space(3))) void lds_t;

__device__ float g_tw[96];   // 8 batches x 12 transform coefficients

// ---- pre-kernel: T[b][i][j] = (1/8) sum_n sign_j(n) sign_i(n) (0.8+0.2 u[b,n,i])
// (verified 12-lane closed form from R0) ----
__global__ void transform_kernel(const float* __restrict__ u) {
    const int t = threadIdx.x;            // 96 used = 8 batches x 12 entries
    if (t >= 96) return;
    const int b = t / 12, e = t - b * 12;
    const int i = e >> 2, j = e & 3;
    float acc = 0.f;
#pragma unroll
    for (int n = 0; n < 8; ++n) {
        const float ci = (n & (4 >> i)) ? 1.f : -1.f;
        const float cj = (j < 3) ? ((n & (4 >> j)) ? 1.f : -1.f) : 1.f;
        const float s  = 0.8f + 0.2f * u[(b * 8 + n) * 3 + i];
        acc += cj * ci * s;
    }
    g_tw[b * 12 + e] = acc * 0.125f;
}

__global__ __launch_bounds__(256, 8) void warp_resample_kernel(
        const float* __restrict__ img, float* __restrict__ out) {
    __shared__ __align__(16) float slab[SLAB];

    const int tid = threadIdx.x;
    // XCD pinning: b = bi&7 -> each XCD-private L2 serves one batch; within an
    // XCD, idx sweeps w then h inside a dblk -> window overlap stays in L2.
    const int bi   = blockIdx.x;
    const int b    = __builtin_amdgcn_readfirstlane(bi & 7);
    const int idx  =  bi >> 3;
    const int wblk =  idx & 3;          // 4 w-tiles of 32
    const int hblk = (idx >> 2) & 15;   // 16 h-tiles of 8
    const int dblk =  idx >> 6;         // 32 d-tiles of 4

    // ---- transform coefficients: uniform scalar loads (L2-hot) ----
    const float* tw = g_tw + b * 12;
    const float t00 = tw[0], t01 = tw[1], t02 = tw[2],  t03 = tw[3];
    const float t10 = tw[4], t11 = tw[5], t12 = tw[6],  t13 = tw[7];
    const float t20 = tw[8], t21 = tw[9], t22 = tw[10], t23 = tw[11];

    const int d0i = dblk << 2, h0i = hblk << 3, w0i = wblk << 5;
    const float inv = 2.0f / 127.0f;
    const float x0 = -1.f + d0i * inv, y0 = -1.f + h0i * inv, z0 = -1.f + w0i * inv;
    // pixel coords at tile origin; per-index pixel delta == t (inv*63.5 == 1)
    const float P0 = (t00 * x0 + t01 * y0 + t02 * z0 + t03 + 1.f) * 63.5f;
    const float P1 = (t10 * x0 + t11 * y0 + t12 * z0 + t13 + 1.f) * 63.5f;
    const float P2 = (t20 * x0 + t21 * y0 + t22 * z0 + t23 + 1.f) * 63.5f;

    // tile bounds via corner extremes (kd<=3, kh<=7, kw<=31)
    const float mn0 = P0 + fminf(0.f,3.f*t00)+fminf(0.f,7.f*t01)+fminf(0.f,31.f*t02);
    const float mx0 = P0 + fmaxf(0.f,3.f*t00)+fmaxf(0.f,7.f*t01)+fmaxf(0.f,31.f*t02);
    const float mn1 = P1 + fminf(0.f,3.f*t10)+fminf(0.f,7.f*t11)+fminf(0.f,31.f*t12);
    const float mx1 = P1 + fmaxf(0.f,3.f*t10)+fmaxf(0.f,7.f*t11)+fmaxf(0.f,31.f*t12);
    const float mn2 = P2 + fminf(0.f,3.f*t20)+fminf(0.f,7.f*t21)+fminf(0.f,31.f*t22);
    const float mx2 = P2 + fmaxf(0.f,3.f*t20)+fmaxf(0.f,7.f*t21)+fmaxf(0.f,31.f*t22);

    const int i0mn = (int)floorf(mn0), i0mx = (int)floorf(mx0);
    const int i1mn = (int)floorf(mn1), i1mx = (int)floorf(mx1);
    const int i2mn = (int)floorf(mn2), i2mx = (int)floorf(mx2);

    // UNCLAMPED window origin (may be negative / past the image)
    const int d_lo = i0mn;
    const int h_lo = i1mn;
    const int ws   = (i2mn - 1) & ~3;          // 4-aligned floor (works for <0)
    const int Sd   = min(i0mx + 2 - d_lo, SD); // staged d-planes <= 9
    const int Sh   = min(i1mx + 2 - h_lo, SH); // staged h-rows   <= 13

    // block-uniform: is the whole staged window inside the image?
    const int allin = __builtin_amdgcn_readfirstlane(
        (d_lo >= 0 && d_lo + Sd <= NS &&
         h_lo >= 0 && h_lo + Sh <= NS &&
         ws   >= 0 && ws + ROW_W <= NS) ? 1 : 0);

    // local-window coordinates (fold window origin into the uniform part)
    const float Pl0 = P0 - (float)d_lo;
    const float Pl1 = P1 - (float)h_lo;
    const float Pl2 = P2 - (float)ws;

    // ---- boundary blocks only: zero-fill slab so OOB taps read 0.0 ----
    if (!allin) {
        float4* p = (float4*)slab;
        for (int i = tid; i < SLAB / 4; i += 256)   // 1170 float4s
            p[i] = make_float4(0.f, 0.f, 0.f, 0.f);
        __syncthreads();   // zeros visible before any LDS-DMA write can land
    }

    // ---- stage slab: Sd*Sh rows of ROW_W floats via global_load_lds x16 ----
    // lane-task: hi = tid/10, chunk = tid%10; LDS float offset = 4*tid exactly,
    // so per-wave LDS base = di*RST + 256*wave (wave-uniform base + lane*16B,
    // as the global_load_lds hardware requires).
    {
        const float* gb = img + (size_t)b * VOX;
        const int hi = tid / 10;
        const int c  = tid - hi * 10;
        const int wvbase = (tid & ~63) << 2;                  // floats
        if (allin) {
            if (hi < Sh) {
                for (int di = 0; di < Sd; ++di) {
                    const float* g = gb + (((d_lo + di) * NS + (h_lo + hi)) * NS
                                           + ws + (c << 2));
                    __builtin_amdgcn_global_load_lds(
                        (gconst_t*)g, (lds_t*)(slab + di * RST + wvbase), 16, 0, 0);
                }
            }
        } else {
            // fully-valid 16B chunks only; skipped chunks keep their zeros
            const int  cc = ws + (c << 2);
            const bool ok = (hi < Sh) && ((unsigned)(h_lo + hi) < NS)
                                      && ((unsigned)cc <= NS - 4);
            if (ok) {
                for (int di = 0; di < Sd; ++di) {
                    if ((unsigned)(d_lo + di) < NS) {
                        const float* g = gb + (((d_lo + di) * NS + (h_lo + hi)) * NS
                                               + cc);
                        __builtin_amdgcn_global_load_lds(
                            (gconst_t*)g, (lds_t*)(slab + di * RST + wvbase), 16, 0, 0);
                    }
                }
            }
        }
    }
    __syncthreads();

    // ---- unified compute: lanes dense along w; 4 voxels along d per thread ----
    // floorf (not (int)cast) so coords floor correctly near 0; every tap's
    // LOCAL index is in-window by the span analysis; OOB-image slots read 0.
    const int wl = tid & 31, hh = tid >> 5;
    float ql0 = Pl0 + hh * t01 + wl * t02;
    float ql1 = Pl1 + hh * t11 + wl * t12;
    float ql2 = Pl2 + hh * t21 + wl * t22;

    float res[4];
#pragma unroll
    for (int k = 0; k < 4; ++k) {
        const float f0 = floorf(ql0), f1 = floorf(ql1), f2 = floorf(ql2);
        const int   i0 = (int)f0,     i1 = (int)f1,     i2 = (int)f2;
        const float r0 = ql0 - f0,    r1 = ql1 - f1,    r2 = ql2 - f2;

        const int base = i0 * RST + i1 * ROW_W + i2;      // const strides
        float a00 = slab[base],           b00 = slab[base + 1];
        float a01 = slab[base + ROW_W],   b01 = slab[base + ROW_W + 1];
        const int base2 = base + RST;
        float a10 = slab[base2],          b10 = slab[base2 + 1];
        float a11 = slab[base2 + ROW_W],  b11 = slab[base2 + ROW_W + 1];

        float e0 = fmaf(r2, b00 - a00, a00);
        float e1 = fmaf(r2, b01 - a01, a01);
        float e2 = fmaf(r2, b10 - a10, a10);
        float e3 = fmaf(r2, b11 - a11, a11);
        float c0 = fmaf(r1, e1 - e0, e0);
        float c1 = fmaf(r1, e3 - e2, e2);
        res[k] = fmaf(r0, c1 - c0, c0);

        ql0 += t00; ql1 += t10; ql2 += t20;
    }

    // stores: wave = 2 h-rows x 32 consecutive w -> coalesced 128B segments
    size_t ob = (((size_t)(b * NS + d0i) * NS + (h0i + hh)) * NS) + w0i + wl;
#pragma unroll
    for (int k = 0; k < 4; ++k)
        out[ob + (size_t)k * NS * NS] = res[k];
}

extern "C" void kernel_launch(void* const* d_in, const int* in_sizes, int n_in,
                              void* d_out, int out_size, void* d_ws, size_t ws_size,
                              hipStream_t stream) {
    const float* img = (const float*)d_in[0];   // [8,128,128,128,1] fp32
    const float* u   = (const float*)d_in[1];   // [8,8,3] fp32
    float* out = (float*)d_out;

    transform_kernel<<<1, 128, 0, stream>>>(u);
    int blocks = NB * 32 * 16 * 4;              // 16384 (b=xcd x 32d x 16h x 4w)
    warp_resample_kernel<<<blocks, 256, 0, stream>>>(img, out);
}

// Round 7
// 124.571 us; speedup vs baseline: 1.0057x; 1.0057x over previous
//
#include <hip/hip_runtime.h>

// input_tensor: [8,128,128,128,1] fp32 ; random_u: [8,8,3] fp32 ; SCALE=0.2
#define NB   8
#define NS   128
#define VOX  (NS*NS*NS)

// R7 = R6 resubmitted verbatim (R6 bench died at container acquisition, both
// attempts; no kernel-side mechanism exists — all-constant loop bounds, no new
// memory accesses vs the passing R3, exact fp32 address math. Infra flake.)
//
// R6 = R3 skeleton (proven best: 32w x 8h x 8d tile, single slab 27KB,
// 6 blocks/CU, 8192 blocks, in-kernel Walsh transform, zero-boundary
// unification) + work-lean inner loop:
//   * float address math: base = (int)(f0*520 + f1*40 + f2) — exact in fp32
//     (max 6759 < 2^24, non-negative) — 2 fma + 1 cvt vs 3 cvt + 4 int ops.
//   * packed-fp32 interpolation: float2 ext-vector lerps -> v_pk_fma_f32 /
//     v_pk_add_f32; pairs (slab[base], slab[base+ROW_W]) match what
//     ds_read2_b32 offset0:0 offset1:40 delivers into a VGPR pair.
// Rationale: R2/R3/R5 proved occupancy (12/24/32 waves), locality, and
// explicit pipelining are all null levers; only straight-line work reduction
// (R1) ever paid. VALUBusy 48% is the largest measured pipe.
// Spans (kd<=7, kh<=7, kw<=31): d/h floor-span <= 11 -> 13 rows; w cols <= 35
// (+align) -> ROW_W=40.
#define SD    13
#define SH    13
#define ROW_W 40
#define RST   (SH*ROW_W)     // 520
#define SLAB  (SD*RST)       // 6760 floats = 27,040 B -> 6 blocks/CU

typedef __attribute__((address_space(1))) const void gconst_t;
typedef __attribute__((address_space(3))) void lds_t;
typedef float vf2 __attribute__((ext_vector_type(2)));

__global__ __launch_bounds__(256) void warp_resample_kernel(
        const float* __restrict__ img, const float* __restrict__ u,
        float* __restrict__ out) {
    __shared__ __align__(16) float slab[SLAB];

    const int tid = threadIdx.x;
    // XCD pinning (neutral-but-harmless, R3): b = bi&7 -> one batch per XCD L2
    const int bi   = blockIdx.x;
    const int b    =  bi & 7;
    const int idx  =  bi >> 3;
    const int wblk =  idx & 3;          // 4 w-tiles of 32
    const int hblk = (idx >> 2) & 15;   // 16 h-tiles of 8
    const int dblk =  idx >> 6;         // 16 d-tiles of 8

    // ---- transform: all lanes uniform (Walsh butterfly; 1/8 folded in) ----
    const float* ub = u + b * 24;
    float T[3][4];
#pragma unroll
    for (int i = 0; i < 3; ++i) {
        float v[8];
#pragma unroll
        for (int n = 0; n < 8; ++n) {
            const float sg = (n & (4 >> i)) ? 1.f : -1.f;
            v[n] = fmaf(sg * 0.025f, ub[n * 3 + i], sg * 0.1f);  // sg*(0.8+0.2u)/8
        }
        const float a0 = v[0] + v[1], a1 = v[2] + v[3];
        const float a2 = v[4] + v[5], a3 = v[6] + v[7];
        const float d0 = v[1] - v[0], d1 = v[3] - v[2];
        const float d2 = v[5] - v[4], d3 = v[7] - v[6];
        const float A01 = a0 + a1, A23 = a2 + a3;
        T[i][0] = A23 - A01;
        T[i][1] = (a1 - a0) + (a3 - a2);
        T[i][2] = (d0 + d1) + (d2 + d3);
        T[i][3] = A01 + A23;
    }
    const float t00 = T[0][0], t01 = T[0][1], t02 = T[0][2], t03 = T[0][3];
    const float t10 = T[1][0], t11 = T[1][1], t12 = T[1][2], t13 = T[1][7-4];
    const float t20 = T[2][0], t21 = T[2][1], t22 = T[2][2], t23 = T[2][3];

    const int d0i = dblk << 3, h0i = hblk << 3, w0i = wblk << 5;
    const float inv = 2.0f / 127.0f;
    const float x0 = -1.f + d0i * inv, y0 = -1.f + h0i * inv, z0 = -1.f + w0i * inv;
    // pixel coords at tile origin; per-index pixel delta == t (inv*63.5 == 1)
    const float P0 = (t00 * x0 + t01 * y0 + t02 * z0 + t03 + 1.f) * 63.5f;
    const float P1 = (t10 * x0 + t11 * y0 + t12 * z0 + t13 + 1.f) * 63.5f;
    const float P2 = (t20 * x0 + t21 * y0 + t22 * z0 + t23 + 1.f) * 63.5f;

    // tile bounds via corner extremes (kd<=7, kh<=7, kw<=31)
    const float mn0 = P0 + fminf(0.f,7.f*t00)+fminf(0.f,7.f*t01)+fminf(0.f,31.f*t02);
    const float mx0 = P0 + fmaxf(0.f,7.f*t00)+fmaxf(0.f,7.f*t01)+fmaxf(0.f,31.f*t02);
    const float mn1 = P1 + fminf(0.f,7.f*t10)+fminf(0.f,7.f*t11)+fminf(0.f,31.f*t12);
    const float mx1 = P1 + fmaxf(0.f,7.f*t10)+fmaxf(0.f,7.f*t11)+fmaxf(0.f,31.f*t12);
    const float mn2 = P2 + fminf(0.f,7.f*t20)+fminf(0.f,7.f*t21)+fminf(0.f,31.f*t22);
    const float mx2 = P2 + fmaxf(0.f,7.f*t20)+fmaxf(0.f,7.f*t21)+fmaxf(0.f,31.f*t22);

    const int i0mn = (int)floorf(mn0), i0mx = (int)floorf(mx0);
    const int i1mn = (int)floorf(mn1), i1mx = (int)floorf(mx1);
    const int i2mn = (int)floorf(mn2), i2mx = (int)floorf(mx2);

    // UNCLAMPED window origin (may be negative / past the image)
    const int d_lo = i0mn;
    const int h_lo = i1mn;
    const int ws   = (i2mn - 1) & ~3;          // 4-aligned floor (works for <0)
    const int Sd   = min(i0mx + 2 - d_lo, SD); // staged d-planes <= 13
    const int Sh   = min(i1mx + 2 - h_lo, SH); // staged h-rows   <= 13

    // block-uniform: is the whole staged window inside the image?
    const int allin = __builtin_amdgcn_readfirstlane(
        (d_lo >= 0 && d_lo + Sd <= NS &&
         h_lo >= 0 && h_lo + Sh <= NS &&
         ws   >= 0 && ws + ROW_W <= NS) ? 1 : 0);

    // local-window coordinates (fold window origin into the uniform part)
    const float Pl0 = P0 - (float)d_lo;
    const float Pl1 = P1 - (float)h_lo;
    const float Pl2 = P2 - (float)ws;

    // ---- boundary blocks only: zero-fill slab so OOB taps read 0.0 ----
    if (!allin) {
        float4* p = (float4*)slab;
        for (int i = tid; i < SLAB / 4; i += 256)   // 1690 float4s
            p[i] = make_float4(0.f, 0.f, 0.f, 0.f);
        __syncthreads();   // zeros visible before any LDS-DMA write can land
    }

    // ---- stage slab: Sd*Sh rows of ROW_W floats via global_load_lds x16 ----
    // lane-task: hi = tid/10, chunk = tid%10; LDS float offset = 4*tid exactly,
    // so per-wave LDS base = di*RST + 256*wave (wave-uniform base + lane*16B).
    {
        const float* gb = img + (size_t)b * VOX;
        const int hi = tid / 10;
        const int c  = tid - hi * 10;
        const int wvbase = (tid & ~63) << 2;                  // floats
        if (allin) {
            if (hi < Sh) {
                for (int di = 0; di < Sd; ++di) {
                    const float* g = gb + (((d_lo + di) * NS + (h_lo + hi)) * NS
                                           + ws + (c << 2));
                    __builtin_amdgcn_global_load_lds(
                        (gconst_t*)g, (lds_t*)(slab + di * RST + wvbase), 16, 0, 0);
                }
            }
        } else {
            // fully-valid 16B chunks only; skipped chunks keep their zeros
            const int  cc = ws + (c << 2);
            const bool ok = (hi < Sh) && ((unsigned)(h_lo + hi) < NS)
                                      && ((unsigned)cc <= NS - 4);
            if (ok) {
                for (int di = 0; di < Sd; ++di) {
                    if ((unsigned)(d_lo + di) < NS) {
                        const float* g = gb + (((d_lo + di) * NS + (h_lo + hi)) * NS
                                               + cc);
                        __builtin_amdgcn_global_load_lds(
                            (gconst_t*)g, (lds_t*)(slab + di * RST + wvbase), 16, 0, 0);
                    }
                }
            }
        }
    }
    __syncthreads();

    // ---- work-lean compute: lanes dense along w; 8 voxels along d/thread ----
    const int wl = tid & 31, hh = tid >> 5;
    float ql0 = Pl0 + hh * t01 + wl * t02;
    float ql1 = Pl1 + hh * t11 + wl * t12;
    float ql2 = Pl2 + hh * t21 + wl * t22;

    float res[8];
#pragma unroll
    for (int k = 0; k < 8; ++k) {
        const float f0 = floorf(ql0), f1 = floorf(ql1), f2 = floorf(ql2);
        const float r0 = ql0 - f0,    r1 = ql1 - f1,    r2 = ql2 - f2;

        // float address build: exact integer arithmetic in fp32 (<= 6759)
        const int base = (int)fmaf(f0, (float)RST, fmaf(f1, (float)ROW_W, f2));
        const int base2 = base + RST;

        // h-pairs straight from ds_read2_b32 (offset0:0 offset1:40) -> VGPR pairs
        vf2 A, Bv, C, D;
        A.x  = slab[base];          A.y  = slab[base + ROW_W];        // a00,a01
        Bv.x = slab[base + 1];      Bv.y = slab[base + ROW_W + 1];    // b00,b01
        C.x  = slab[base2];         C.y  = slab[base2 + ROW_W];       // a10,a11
        D.x  = slab[base2 + 1];     D.y  = slab[base2 + ROW_W + 1];   // b10,b11

        const vf2 rr2 = {r2, r2};
        const vf2 rr1 = {r1, r1};
        const vf2 U = A + rr2 * (Bv - A);   // w-lerp, plane i0:   (e0, e1)
        const vf2 V = C + rr2 * (D  - C);   // w-lerp, plane i0+1: (e2, e3)
        const vf2 X = {U.x, V.x};           // (e0, e2)  — op_sel-foldable
        const vf2 Y = {U.y, V.y};           // (e1, e3)
        const vf2 Cv = X + rr1 * (Y - X);   // h-lerp both planes: (c0, c1)
        res[k] = fmaf(r0, Cv.y - Cv.x, Cv.x);   // d-lerp

        ql0 += t00; ql1 += t10; ql2 += t20;
    }

    // stores: wave = 2 h-rows x 32 consecutive w -> coalesced 128B segments
    size_t ob = (((size_t)(b * NS + d0i) * NS + (h0i + hh)) * NS) + w0i + wl;
#pragma unroll
    for (int k = 0; k < 8; ++k)
        out[ob + (size_t)k * NS * NS] = res[k];
}

extern "C" void kernel_launch(void* const* d_in, const int* in_sizes, int n_in,
                              void* d_out, int out_size, void* d_ws, size_t ws_size,
                              hipStream_t stream) {
    const float* img = (const float*)d_in[0];   // [8,128,128,128,1] fp32
    const float* u   = (const float*)d_in[1];   // [8,8,3] fp32
    float* out = (float*)d_out;

    int blocks = NB * 16 * 16 * 4;              // 8192 (b=xcd x 16d x 16h x 4w)
    warp_resample_kernel<<<blocks, 256, 0, stream>>>(img, u, out);
}